// Round 3
// baseline (1535.389 us; speedup 1.0000x reference)
//
#include <hip/hip_runtime.h>
#include <hip/hip_bf16.h>

#define NN 65536
#define DM 1024
#define NH 16
#define KNB 4096
#define DEX 20
#define EPSV 1e-5f

typedef __attribute__((ext_vector_type(8))) short bf16x8;
typedef __attribute__((ext_vector_type(4))) float f32x4;

__device__ __forceinline__ unsigned short f2bf(float f){
  unsigned u = __builtin_bit_cast(unsigned, f);
  u += 0x7fffu + ((u >> 16) & 1u);
  return (unsigned short)(u >> 16);
}
__device__ __forceinline__ float bf2f(unsigned short s){
  return __builtin_bit_cast(float, ((unsigned)s) << 16);
}
__device__ __forceinline__ float wred(float v){
  #pragma unroll
  for (int s = 32; s; s >>= 1) v += __shfl_down(v, s);
  return v;
}

// ---------- scatter local_bias rows into extra (N x 20); extra pre-zeroed ----------
__global__ void k_scatter(const float* __restrict__ lb, const int* __restrict__ nidx,
                          float* __restrict__ extra){
  int i = blockIdx.x * 256 + threadIdx.x;
  if (i < KNB * DEX){
    int j = i / DEX, col = i - j * DEX;
    extra[(size_t)nidx[j] * DEX + col] = lb[i];
  }
}

// ---------- convert MLP weights to bf16: Wcomb (2048x1024) + W2b (1024x1024) ----------
__global__ void k_convw(const float* __restrict__ gateW, const float* __restrict__ fuseW1,
                        const float* __restrict__ fuseW2,
                        unsigned short* __restrict__ Wcomb, unsigned short* __restrict__ W2b){
  int i = blockIdx.x * 256 + threadIdx.x;
  if (i < 2048 * 1024){
    int o = i >> 10, d = i & 1023;
    float v = (o < 1024) ? gateW[(size_t)o * 2048 + d] : fuseW1[(size_t)(o - 1024) * 2048 + d];
    Wcomb[i] = f2bf(v);
  } else {
    int j = i - 2048 * 1024;
    W2b[j] = f2bf(fuseW2[j]);
  }
}

// ---------- LN of center row (norm_c) -> hcln[1024] ----------
__global__ void k_cln(const float* __restrict__ h, const int* __restrict__ cidx,
                      const float* __restrict__ cw, const float* __restrict__ cb,
                      float* __restrict__ hcln){
  int t = threadIdx.x, lane = t & 63, wid = t >> 6;
  int c = *cidx;
  const float4 x = *(const float4*)(h + (size_t)c * DM + t * 4);
  float s  = x.x + x.y + x.z + x.w;
  float ss = x.x * x.x + x.y * x.y + x.z * x.z + x.w * x.w;
  __shared__ float rs[4], rq[4];
  s = wred(s); ss = wred(ss);
  if (lane == 0){ rs[wid] = s; rq[wid] = ss; }
  __syncthreads();
  float mean = (rs[0] + rs[1] + rs[2] + rs[3]) * (1.0f / DM);
  float var  = (rq[0] + rq[1] + rq[2] + rq[3]) * (1.0f / DM) - mean * mean;
  float rstd = rsqrtf(var + EPSV);
  const float4 w = *(const float4*)(cw + t * 4);
  const float4 b = *(const float4*)(cb + t * 4);
  float4 o;
  o.x = (x.x - mean) * rstd * w.x + b.x;
  o.y = (x.y - mean) * rstd * w.y + b.y;
  o.z = (x.z - mean) * rstd * w.z + b.z;
  o.w = (x.w - mean) * rstd * w.w + b.w;
  *(float4*)(hcln + t * 4) = o;
}

// ---------- q[o] = hcln . Wq[o,:]   (64 blocks x 256; wave-split-K, coalesced) ----------
__global__ void k_q(const float* __restrict__ hcln, const float* __restrict__ Wq,
                    float* __restrict__ q){
  int lane = threadIdx.x & 63, wid = threadIdx.x >> 6;
  float hv[16];
  #pragma unroll
  for (int j = 0; j < 16; j++) hv[j] = hcln[lane + 64 * j];
  #pragma unroll
  for (int oi = 0; oi < 4; oi++){
    int o = blockIdx.x * 16 + wid * 4 + oi;
    const float* wr = Wq + (size_t)o * DM;
    float a = 0.f;
    #pragma unroll
    for (int j = 0; j < 16; j++) a = fmaf(hv[j], wr[lane + 64 * j], a);
    a = wred(a);
    if (lane == 0) q[o] = a;
  }
}

// ---------- qkt[hh,i] = (sum_d q[hh*64+d] * Wk[hh*64+d, i]) / 8 ----------
__global__ void k_qkt(const float* __restrict__ q, const float* __restrict__ Wk,
                      float* __restrict__ qkt){
  int idx = blockIdx.x * 256 + threadIdx.x;   // 0..16383
  int hh = idx >> 10, i = idx & 1023;
  float a = 0.f;
  #pragma unroll 8
  for (int d = 0; d < 64; d++) a = fmaf(q[hh * 64 + d], Wk[(size_t)(hh * 64 + d) * DM + i], a);
  qkt[idx] = a * 0.125f;
}

// ---------- big row pass: LN stats, logits (16 heads), bias, h->bf16 ----------
__global__ void k_rowpass(const float* __restrict__ h, const float* __restrict__ aw,
                          const float* __restrict__ ab, const float* __restrict__ rbf,
                          const float* __restrict__ seqsep, const float* __restrict__ extra,
                          const float* __restrict__ wbias, const float* __restrict__ qkt,
                          float* __restrict__ logits, float* __restrict__ meanb,
                          float* __restrict__ rstdb, unsigned short* __restrict__ hbf){
  const int t = threadIdx.x, lane = t & 63, wid = t >> 6;
  float qs[NH][4];
  #pragma unroll
  for (int hh = 0; hh < NH; hh++){
    const float4 v = *(const float4*)(qkt + hh * DM + t * 4);
    qs[hh][0] = v.x; qs[hh][1] = v.y; qs[hh][2] = v.z; qs[hh][3] = v.w;
  }
  const float4 w = *(const float4*)(aw + t * 4);
  const float4 b = *(const float4*)(ab + t * 4);
  __shared__ float rs[4], rq[4];
  __shared__ float pl[4][NH];
  for (int r = 0; r < 8; r++){
    const int n = blockIdx.x * 8 + r;
    const float4 x = *(const float4*)(h + (size_t)n * DM + t * 4);
    float s  = x.x + x.y + x.z + x.w;
    float ss = x.x * x.x + x.y * x.y + x.z * x.z + x.w * x.w;
    s = wred(s); ss = wred(ss);
    if (lane == 0){ rs[wid] = s; rq[wid] = ss; }
    __syncthreads();
    const float mean = (rs[0] + rs[1] + rs[2] + rs[3]) * (1.0f / DM);
    const float var  = (rq[0] + rq[1] + rq[2] + rq[3]) * (1.0f / DM) - mean * mean;
    const float rstd = rsqrtf(var + EPSV);
    ushort4 hb;
    hb.x = f2bf(x.x); hb.y = f2bf(x.y); hb.z = f2bf(x.z); hb.w = f2bf(x.w);
    *(ushort4*)(hbf + (size_t)n * DM + t * 4) = hb;
    if (t == 0){ meanb[n] = mean; rstdb[n] = rstd; }
    const float l0 = (x.x - mean) * rstd * w.x + b.x;
    const float l1 = (x.y - mean) * rstd * w.y + b.y;
    const float l2 = (x.z - mean) * rstd * w.z + b.z;
    const float l3 = (x.w - mean) * rstd * w.w + b.w;
    float p[NH];
    #pragma unroll
    for (int hh = 0; hh < NH; hh++)
      p[hh] = fmaf(l0, qs[hh][0], fmaf(l1, qs[hh][1], fmaf(l2, qs[hh][2], l3 * qs[hh][3])));
    #pragma unroll
    for (int sft = 32; sft; sft >>= 1){
      #pragma unroll
      for (int hh = 0; hh < NH; hh++) p[hh] += __shfl_down(p[hh], sft);
    }
    if (lane == 0){
      #pragma unroll
      for (int hh = 0; hh < NH; hh++) pl[wid][hh] = p[hh];
    }
    __syncthreads();
    if (t < NH){
      float v = pl[0][t] + pl[1][t] + pl[2][t] + pl[3][t];
      const float* wb = wbias + t * 40;
      float bb = 0.f;
      #pragma unroll
      for (int j = 0; j < 16; j++) bb = fmaf(rbf[(size_t)n * 16 + j], wb[j], bb);
      #pragma unroll
      for (int j = 0; j < 4; j++)  bb = fmaf(seqsep[(size_t)n * 4 + j], wb[16 + j], bb);
      #pragma unroll
      for (int j = 0; j < 20; j++) bb = fmaf(extra[(size_t)n * DEX + j], wb[20 + j], bb);
      logits[(size_t)t * NN + n] = v + bb;
    }
    __syncthreads();
  }
}

// ---------- per-head softmax stats: m, s ----------
__global__ void k_smstats(const float* __restrict__ logits, float* __restrict__ ms){
  const int hh = blockIdx.x, t = threadIdx.x, lane = t & 63, wid = t >> 6;
  __shared__ float red[16];
  __shared__ float bcast;
  const float* lp = logits + (size_t)hh * NN;
  float m = -3.0e38f;
  for (int n = t; n < NN; n += 1024) m = fmaxf(m, lp[n]);
  #pragma unroll
  for (int s = 32; s; s >>= 1) m = fmaxf(m, __shfl_down(m, s));
  if (lane == 0) red[wid] = m;
  __syncthreads();
  if (t == 0){
    float mm = red[0];
    #pragma unroll
    for (int i = 1; i < 16; i++) mm = fmaxf(mm, red[i]);
    bcast = mm;
  }
  __syncthreads();
  m = bcast;
  float s = 0.f;
  for (int n = t; n < NN; n += 1024) s += __expf(lp[n] - m);
  s = wred(s);
  if (lane == 0) red[wid] = s;
  __syncthreads();
  if (t == 0){
    float sv = 0.f;
    #pragma unroll
    for (int i = 0; i < 16; i++) sv += red[i];
    ms[hh] = m; ms[16 + hh] = sv;
  }
}

// ---------- u partials: upart[b,hh,d] = sum_rows exp(logit-m) * LN(h) ----------
#define UB 512
__global__ void k_upart(const unsigned short* __restrict__ hbf, const float* __restrict__ meanb,
                        const float* __restrict__ rstdb, const float* __restrict__ aw,
                        const float* __restrict__ ab, const float* __restrict__ logits,
                        const float* __restrict__ ms, float* __restrict__ upart){
  const int t = threadIdx.x, bb = blockIdx.x;
  const float4 w  = *(const float4*)(aw + t * 4);
  const float4 bv = *(const float4*)(ab + t * 4);
  float mh[NH];
  #pragma unroll
  for (int hh = 0; hh < NH; hh++) mh[hh] = ms[hh];
  float acc[NH][4];
  #pragma unroll
  for (int hh = 0; hh < NH; hh++){ acc[hh][0] = 0.f; acc[hh][1] = 0.f; acc[hh][2] = 0.f; acc[hh][3] = 0.f; }
  #pragma unroll 2
  for (int r = 0; r < NN / UB; r++){
    const int n = bb * (NN / UB) + r;
    const float mean = meanb[n], rstd = rstdb[n];
    const ushort4 hb = *(const ushort4*)(hbf + (size_t)n * DM + t * 4);
    const float l0 = (bf2f(hb.x) - mean) * rstd * w.x + bv.x;
    const float l1 = (bf2f(hb.y) - mean) * rstd * w.y + bv.y;
    const float l2 = (bf2f(hb.z) - mean) * rstd * w.z + bv.z;
    const float l3 = (bf2f(hb.w) - mean) * rstd * w.w + bv.w;
    #pragma unroll
    for (int hh = 0; hh < NH; hh++){
      const float e = __expf(logits[(size_t)hh * NN + n] - mh[hh]);
      acc[hh][0] = fmaf(e, l0, acc[hh][0]);
      acc[hh][1] = fmaf(e, l1, acc[hh][1]);
      acc[hh][2] = fmaf(e, l2, acc[hh][2]);
      acc[hh][3] = fmaf(e, l3, acc[hh][3]);
    }
  }
  #pragma unroll
  for (int hh = 0; hh < NH; hh++){
    float4 o; o.x = acc[hh][0]; o.y = acc[hh][1]; o.z = acc[hh][2]; o.w = acc[hh][3];
    *(float4*)(upart + ((size_t)bb * NH + hh) * DM + t * 4) = o;
  }
}

// ---------- reduce partials, normalize by s ----------
__global__ void k_ureduce(const float* __restrict__ upart, const float* __restrict__ ms,
                          float* __restrict__ u){
  const int idx = blockIdx.x * 256 + threadIdx.x;   // 0..16383
  const int hh = idx >> 10;
  float s = 0.f;
  for (int b = 0; b < UB; b++) s += upart[(size_t)b * (NH * DM) + idx];
  u[idx] = s / ms[16 + hh];
}

// ---------- out_center[o] = u[head(o),:] . Wv[o,:] ----------
__global__ void k_oc(const float* __restrict__ u, const float* __restrict__ Wv,
                     float* __restrict__ oc){
  int lane = threadIdx.x & 63, wid = threadIdx.x >> 6;
  #pragma unroll
  for (int oi = 0; oi < 4; oi++){
    int o = blockIdx.x * 16 + wid * 4 + oi;
    const float* ur = u + (size_t)(o >> 6) * DM;
    const float* wr = Wv + (size_t)o * DM;
    float a = 0.f;
    #pragma unroll
    for (int j = 0; j < 16; j++) a = fmaf(ur[lane + 64 * j], wr[lane + 64 * j], a);
    a = wred(a);
    if (lane == 0) oc[o] = a;
  }
}

// ---------- hcnew[o] = h[c,o] + 0.5 * oc . Wo[o,:] ----------
__global__ void k_delta(const float* __restrict__ oc, const float* __restrict__ Wo,
                        const float* __restrict__ h, const int* __restrict__ cidx,
                        float* __restrict__ hcnew){
  int lane = threadIdx.x & 63, wid = threadIdx.x >> 6;
  int c = *cidx;
  float ov[16];
  #pragma unroll
  for (int j = 0; j < 16; j++) ov[j] = oc[lane + 64 * j];
  #pragma unroll
  for (int oi = 0; oi < 4; oi++){
    int o = blockIdx.x * 16 + wid * 4 + oi;
    const float* wr = Wo + (size_t)o * DM;
    float a = 0.f;
    #pragma unroll
    for (int j = 0; j < 16; j++) a = fmaf(ov[j], wr[lane + 64 * j], a);
    a = wred(a);
    if (lane == 0) hcnew[o] = h[(size_t)c * DM + o] + 0.5f * a;
  }
}

// ---------- rank-1 column biases: gbtot/fbtot ----------
__global__ void k_gbfb(const float* __restrict__ hcnew, const float* __restrict__ gateW,
                       const float* __restrict__ gateB, const float* __restrict__ fuseW1,
                       const float* __restrict__ fuseB1, float* __restrict__ gbtot,
                       float* __restrict__ fbtot){
  int lane = threadIdx.x & 63, wid = threadIdx.x >> 6;
  float hv[16];
  #pragma unroll
  for (int j = 0; j < 16; j++) hv[j] = hcnew[lane + 64 * j];
  #pragma unroll
  for (int oi = 0; oi < 4; oi++){
    int o = blockIdx.x * 16 + wid * 4 + oi;
    const float* gr = gateW + (size_t)o * 2048 + 1024;
    const float* fr = fuseW1 + (size_t)o * 2048 + 1024;
    float ga = 0.f, fa = 0.f;
    #pragma unroll
    for (int j = 0; j < 16; j++){
      ga = fmaf(hv[j], gr[lane + 64 * j], ga);
      fa = fmaf(hv[j], fr[lane + 64 * j], fa);
    }
    ga = wred(ga); fa = wred(fa);
    if (lane == 0){ gbtot[o] = ga + gateB[o]; fbtot[o] = fa + fuseB1[o]; }
  }
}

// ---------- MFMA GEMM: C[m,n] = sum_k A[m,k]*B[n,k]
// 128x128 tile, BK=32, 2-phase double-buffered prefetch (T3 minimum recipe),
// 2-way-free XOR swizzle (chunk ^= (row>>1)&3), XCD-chunk blockIdx remap. ----------
#define BMT 128
#define BKK 32
#define GLL16(gp, lp) __builtin_amdgcn_global_load_lds((const __attribute__((address_space(1))) void*)(gp), (__attribute__((address_space(3))) void*)(lp), 16, 0, 0)

template<int MODE>
__launch_bounds__(256)
__global__ void k_gemm(const unsigned short* __restrict__ A, const unsigned short* __restrict__ B,
                       const float* __restrict__ bias0, const float* __restrict__ bias1,
                       const float* __restrict__ hsrc, const unsigned short* __restrict__ gate,
                       unsigned short* __restrict__ og, unsigned short* __restrict__ ot,
                       float* __restrict__ of){
  __shared__ __attribute__((aligned(16))) unsigned short lA[2][BMT * BKK];
  __shared__ __attribute__((aligned(16))) unsigned short lB[2][BMT * BKK];
  const int NWG = (MODE == 0) ? 8192 : 4096;
  const int NYT = (MODE == 0) ? 16 : 8;
  const int bid = blockIdx.x;
  const int remap = (bid & 7) * (NWG >> 3) + (bid >> 3);   // XCD-chunk swizzle (bijective)
  const int m0 = (remap / NYT) * BMT, n0 = (remap % NYT) * BMT;

  const int tid = threadIdx.x, lane = tid & 63;
  const int wid = tid >> 6, wm = wid >> 1, wn = wid & 1;
  f32x4 acc[4][4];
  #pragma unroll
  for (int i = 0; i < 4; i++){
    #pragma unroll
    for (int j = 0; j < 4; j++){ acc[i][j][0] = 0.f; acc[i][j][1] = 0.f; acc[i][j][2] = 0.f; acc[i][j][3] = 0.f; }
  }

  // staging: thread covers rows {rs, rs+64}, chunk cch (16B). Source col is
  // pre-swizzled so linear LDS dest holds LDS[r][c] = G[r][c ^ ((r>>1)&3)].
  const int rs  = tid >> 2;                      // 0..63
  const int cch = tid & 3;                       // chunk 0..3
  const int csw = (cch ^ ((rs >> 1) & 3)) << 3;  // swizzled source col (elements)
  const unsigned short* Abase = A + (size_t)(m0 + rs) * DM + csw;
  const unsigned short* Bbase = B + (size_t)(n0 + rs) * DM + csw;

  // read-side: fragment row fr = lane&15 (block base multiple of 16), chunk = lane>>4
  const int fr = lane & 15;
  const int sc = ((lane >> 4) ^ ((fr >> 1) & 3)) << 3;   // swizzled element offset
  const int rA0 = (wm * 64 + fr) * BKK + sc;
  const int rB0 = (wn * 64 + fr) * BKK + sc;

  auto stage = [&](int buf, int kt){
    GLL16(Abase + kt,            &lA[buf][tid * 8]);
    GLL16(Abase + 64 * DM + kt,  &lA[buf][2048 + tid * 8]);
    GLL16(Bbase + kt,            &lB[buf][tid * 8]);
    GLL16(Bbase + 64 * DM + kt,  &lB[buf][2048 + tid * 8]);
  };
  auto compute = [&](int buf){
    bf16x8 af[4], bfr[4];
    #pragma unroll
    for (int mi = 0; mi < 4; mi++) af[mi] = *(const bf16x8*)(&lA[buf][rA0 + mi * 16 * BKK]);
    #pragma unroll
    for (int nj = 0; nj < 4; nj++) bfr[nj] = *(const bf16x8*)(&lB[buf][rB0 + nj * 16 * BKK]);
    #pragma unroll
    for (int mi = 0; mi < 4; mi++){
      #pragma unroll
      for (int nj = 0; nj < 4; nj++)
        acc[mi][nj] = __builtin_amdgcn_mfma_f32_16x16x32_bf16(af[mi], bfr[nj], acc[mi][nj], 0, 0, 0);
    }
  };

  stage(0, 0);
  __syncthreads();              // vmcnt(0) drain: buf0 ready
  int cur = 0;
  for (int kt = BKK; kt < DM; kt += BKK){
    stage(cur ^ 1, kt);         // issue next-tile loads (in flight during compute)
    compute(cur);
    __syncthreads();            // drain: next buf ready; cur reads done before overwrite
    cur ^= 1;
  }
  compute(cur);                 // last tile

  const int r0 = (lane >> 4) * 4, cc = lane & 15;
  #pragma unroll
  for (int mi = 0; mi < 4; mi++){
    #pragma unroll
    for (int nj = 0; nj < 4; nj++){
      const int gmb = m0 + wm * 64 + mi * 16 + r0;
      const int gn  = n0 + wn * 64 + nj * 16 + cc;
      #pragma unroll
      for (int r = 0; r < 4; r++){
        const int gm = gmb + r;
        const float x = acc[mi][nj][r];
        if (MODE == 0){
          if (gn < 1024){
            const float v = x + bias0[gn];
            og[(size_t)gm * DM + gn] = f2bf(1.0f / (1.0f + __expf(-v)));
          } else {
            const float v = x + bias1[gn - 1024];
            ot[(size_t)gm * DM + (gn - 1024)] = f2bf(v / (1.0f + __expf(-v)));
          }
        } else {
          const float v = x + bias0[gn];
          const float g = bf2f(gate[(size_t)gm * DM + gn]);
          of[(size_t)gm * DM + gn] = hsrc[(size_t)gm * DM + gn] + 0.5f * g * v;
        }
      }
    }
  }
}

// ---------- overwrite center row ----------
__global__ void k_fixc(const float* __restrict__ hcnew, const int* __restrict__ cidx,
                       float* __restrict__ out){
  int t = threadIdx.x;
  int c = *cidx;
  out[(size_t)c * DM + t] = hcnew[t];
}

extern "C" void kernel_launch(void* const* d_in, const int* in_sizes, int n_in,
                              void* d_out, int out_size, void* d_ws, size_t ws_size,
                              hipStream_t stream){
  const float* h      = (const float*)d_in[0];
  const float* rbf    = (const float*)d_in[1];
  const float* seqsep = (const float*)d_in[2];
  const float* localb = (const float*)d_in[3];
  const float* ncw    = (const float*)d_in[4];
  const float* ncb    = (const float*)d_in[5];
  const float* naw    = (const float*)d_in[6];
  const float* nab    = (const float*)d_in[7];
  const float* Wq     = (const float*)d_in[8];
  const float* Wk     = (const float*)d_in[9];
  const float* Wv     = (const float*)d_in[10];
  const float* Wo     = (const float*)d_in[11];
  const float* Wbias  = (const float*)d_in[12];
  const float* gateW  = (const float*)d_in[13];
  const float* gateB  = (const float*)d_in[14];
  const float* fuseW1 = (const float*)d_in[15];
  const float* fuseB1 = (const float*)d_in[16];
  const float* fuseW2 = (const float*)d_in[17];
  const float* fuseB2 = (const float*)d_in[18];
  const int*   nbr    = (const int*)d_in[19];
  const int*   cidx   = (const int*)d_in[20];
  float* out = (float*)d_out;

  char* p = (char*)d_ws;
  auto alloc = [&](size_t nb){ char* r = p; p += (nb + 255) & ~(size_t)255; return r; };
  float* extra  = (float*)alloc((size_t)NN * DEX * 4);
  float* logits = (float*)alloc((size_t)NH * NN * 4);
  float* meanb  = (float*)alloc((size_t)NN * 4);
  float* rstdb  = (float*)alloc((size_t)NN * 4);
  float* ms     = (float*)alloc(32 * 4);
  float* qkt    = (float*)alloc(NH * DM * 4);
  float* u      = (float*)alloc(NH * DM * 4);
  float* hcln   = (float*)alloc(DM * 4);
  float* qv     = (float*)alloc(DM * 4);
  float* oc     = (float*)alloc(DM * 4);
  float* hcnew  = (float*)alloc(DM * 4);
  float* gbtot  = (float*)alloc(DM * 4);
  float* fbtot  = (float*)alloc(DM * 4);
  float* upart  = (float*)alloc((size_t)UB * NH * DM * 4);
  unsigned short* Wcomb = (unsigned short*)alloc((size_t)2048 * 1024 * 2);
  unsigned short* W2b   = (unsigned short*)alloc((size_t)1024 * 1024 * 2);
  unsigned short* hbf   = (unsigned short*)alloc((size_t)NN * DM * 2);
  unsigned short* gateb = (unsigned short*)alloc((size_t)NN * DM * 2);
  unsigned short* t1    = (unsigned short*)alloc((size_t)NN * DM * 2);
  if ((size_t)(p - (char*)d_ws) > ws_size) return;  // clean fail instead of corruption

  hipMemsetAsync(extra, 0, (size_t)NN * DEX * 4, stream);
  k_scatter<<<(KNB * DEX + 255) / 256, 256, 0, stream>>>(localb, nbr, extra);
  k_convw<<<(3 * 1024 * 1024) / 256, 256, 0, stream>>>(gateW, fuseW1, fuseW2, Wcomb, W2b);
  k_cln<<<1, 256, 0, stream>>>(h, cidx, ncw, ncb, hcln);
  k_q<<<64, 256, 0, stream>>>(hcln, Wq, qv);
  k_qkt<<<64, 256, 0, stream>>>(qv, Wk, qkt);
  k_rowpass<<<NN / 8, 256, 0, stream>>>(h, naw, nab, rbf, seqsep, extra, Wbias, qkt,
                                        logits, meanb, rstdb, hbf);
  k_smstats<<<16, 1024, 0, stream>>>(logits, ms);
  k_upart<<<UB, 256, 0, stream>>>(hbf, meanb, rstdb, naw, nab, logits, ms, upart);
  k_ureduce<<<64, 256, 0, stream>>>(upart, ms, u);
  k_oc<<<64, 256, 0, stream>>>(u, Wv, oc);
  k_delta<<<64, 256, 0, stream>>>(oc, Wo, h, cidx, hcnew);
  k_gbfb<<<64, 256, 0, stream>>>(hcnew, gateW, gateB, fuseW1, fuseB1, gbtot, fbtot);
  k_gemm<0><<<8192, 256, 0, stream>>>(hbf, Wcomb, gbtot, fbtot, nullptr, nullptr, gateb, t1, nullptr);
  k_gemm<1><<<4096, 256, 0, stream>>>(t1, W2b, fuseB2, nullptr, h, gateb, nullptr, nullptr, out);
  k_fixc<<<1, 1024, 0, stream>>>(hcnew, cidx, out);
}

// Round 4
// 1273.463 us; speedup vs baseline: 1.2057x; 1.2057x over previous
//
#include <hip/hip_runtime.h>
#include <hip/hip_bf16.h>

#define NN 65536
#define DM 1024
#define NH 16
#define KNB 4096
#define DEX 20
#define EPSV 1e-5f

typedef __attribute__((ext_vector_type(8))) short bf16x8;
typedef __attribute__((ext_vector_type(4))) float f32x4;

__device__ __forceinline__ unsigned short f2bf(float f){
  unsigned u = __builtin_bit_cast(unsigned, f);
  u += 0x7fffu + ((u >> 16) & 1u);
  return (unsigned short)(u >> 16);
}
__device__ __forceinline__ float bf2f(unsigned short s){
  return __builtin_bit_cast(float, ((unsigned)s) << 16);
}
__device__ __forceinline__ float wred(float v){
  #pragma unroll
  for (int s = 32; s; s >>= 1) v += __shfl_down(v, s);
  return v;
}

// ---------- scatter local_bias rows into extra (N x 20); extra pre-zeroed ----------
__global__ void k_scatter(const float* __restrict__ lb, const int* __restrict__ nidx,
                          float* __restrict__ extra){
  int i = blockIdx.x * 256 + threadIdx.x;
  if (i < KNB * DEX){
    int j = i / DEX, col = i - j * DEX;
    extra[(size_t)nidx[j] * DEX + col] = lb[i];
  }
}

// ---------- convert MLP weights to bf16: Wcomb (2048x1024) + W2b (1024x1024) ----------
__global__ void k_convw(const float* __restrict__ gateW, const float* __restrict__ fuseW1,
                        const float* __restrict__ fuseW2,
                        unsigned short* __restrict__ Wcomb, unsigned short* __restrict__ W2b){
  int i = blockIdx.x * 256 + threadIdx.x;
  if (i < 2048 * 1024){
    int o = i >> 10, d = i & 1023;
    float v = (o < 1024) ? gateW[(size_t)o * 2048 + d] : fuseW1[(size_t)(o - 1024) * 2048 + d];
    Wcomb[i] = f2bf(v);
  } else {
    int j = i - 2048 * 1024;
    W2b[j] = f2bf(fuseW2[j]);
  }
}

// ---------- LN of center row (norm_c) -> hcln[1024] ----------
__global__ void k_cln(const float* __restrict__ h, const int* __restrict__ cidx,
                      const float* __restrict__ cw, const float* __restrict__ cb,
                      float* __restrict__ hcln){
  int t = threadIdx.x, lane = t & 63, wid = t >> 6;
  int c = *cidx;
  const float4 x = *(const float4*)(h + (size_t)c * DM + t * 4);
  float s  = x.x + x.y + x.z + x.w;
  float ss = x.x * x.x + x.y * x.y + x.z * x.z + x.w * x.w;
  __shared__ float rs[4], rq[4];
  s = wred(s); ss = wred(ss);
  if (lane == 0){ rs[wid] = s; rq[wid] = ss; }
  __syncthreads();
  float mean = (rs[0] + rs[1] + rs[2] + rs[3]) * (1.0f / DM);
  float var  = (rq[0] + rq[1] + rq[2] + rq[3]) * (1.0f / DM) - mean * mean;
  float rstd = rsqrtf(var + EPSV);
  const float4 w = *(const float4*)(cw + t * 4);
  const float4 b = *(const float4*)(cb + t * 4);
  float4 o;
  o.x = (x.x - mean) * rstd * w.x + b.x;
  o.y = (x.y - mean) * rstd * w.y + b.y;
  o.z = (x.z - mean) * rstd * w.z + b.z;
  o.w = (x.w - mean) * rstd * w.w + b.w;
  *(float4*)(hcln + t * 4) = o;
}

// ---------- q[o] = hcln . Wq[o,:]   (64 blocks x 256; wave-split-K, coalesced) ----------
__global__ void k_q(const float* __restrict__ hcln, const float* __restrict__ Wq,
                    float* __restrict__ q){
  int lane = threadIdx.x & 63, wid = threadIdx.x >> 6;
  float hv[16];
  #pragma unroll
  for (int j = 0; j < 16; j++) hv[j] = hcln[lane + 64 * j];
  #pragma unroll
  for (int oi = 0; oi < 4; oi++){
    int o = blockIdx.x * 16 + wid * 4 + oi;
    const float* wr = Wq + (size_t)o * DM;
    float a = 0.f;
    #pragma unroll
    for (int j = 0; j < 16; j++) a = fmaf(hv[j], wr[lane + 64 * j], a);
    a = wred(a);
    if (lane == 0) q[o] = a;
  }
}

// ---------- qkt[hh,i] = (sum_d q[hh*64+d] * Wk[hh*64+d, i]) / 8 ----------
__global__ void k_qkt(const float* __restrict__ q, const float* __restrict__ Wk,
                      float* __restrict__ qkt){
  int idx = blockIdx.x * 256 + threadIdx.x;   // 0..16383
  int hh = idx >> 10, i = idx & 1023;
  float a = 0.f;
  #pragma unroll 8
  for (int d = 0; d < 64; d++) a = fmaf(q[hh * 64 + d], Wk[(size_t)(hh * 64 + d) * DM + i], a);
  qkt[idx] = a * 0.125f;
}

// ---------- big row pass: LN stats, logits (16 heads), bias, h->bf16 ----------
__global__ void k_rowpass(const float* __restrict__ h, const float* __restrict__ aw,
                          const float* __restrict__ ab, const float* __restrict__ rbf,
                          const float* __restrict__ seqsep, const float* __restrict__ extra,
                          const float* __restrict__ wbias, const float* __restrict__ qkt,
                          float* __restrict__ logits, float* __restrict__ meanb,
                          float* __restrict__ rstdb, unsigned short* __restrict__ hbf){
  const int t = threadIdx.x, lane = t & 63, wid = t >> 6;
  float qs[NH][4];
  #pragma unroll
  for (int hh = 0; hh < NH; hh++){
    const float4 v = *(const float4*)(qkt + hh * DM + t * 4);
    qs[hh][0] = v.x; qs[hh][1] = v.y; qs[hh][2] = v.z; qs[hh][3] = v.w;
  }
  const float4 w = *(const float4*)(aw + t * 4);
  const float4 b = *(const float4*)(ab + t * 4);
  __shared__ float rs[4], rq[4];
  __shared__ float pl[4][NH];
  for (int r = 0; r < 8; r++){
    const int n = blockIdx.x * 8 + r;
    const float4 x = *(const float4*)(h + (size_t)n * DM + t * 4);
    float s  = x.x + x.y + x.z + x.w;
    float ss = x.x * x.x + x.y * x.y + x.z * x.z + x.w * x.w;
    s = wred(s); ss = wred(ss);
    if (lane == 0){ rs[wid] = s; rq[wid] = ss; }
    __syncthreads();
    const float mean = (rs[0] + rs[1] + rs[2] + rs[3]) * (1.0f / DM);
    const float var  = (rq[0] + rq[1] + rq[2] + rq[3]) * (1.0f / DM) - mean * mean;
    const float rstd = rsqrtf(var + EPSV);
    ushort4 hb;
    hb.x = f2bf(x.x); hb.y = f2bf(x.y); hb.z = f2bf(x.z); hb.w = f2bf(x.w);
    *(ushort4*)(hbf + (size_t)n * DM + t * 4) = hb;
    if (t == 0){ meanb[n] = mean; rstdb[n] = rstd; }
    const float l0 = (x.x - mean) * rstd * w.x + b.x;
    const float l1 = (x.y - mean) * rstd * w.y + b.y;
    const float l2 = (x.z - mean) * rstd * w.z + b.z;
    const float l3 = (x.w - mean) * rstd * w.w + b.w;
    float p[NH];
    #pragma unroll
    for (int hh = 0; hh < NH; hh++)
      p[hh] = fmaf(l0, qs[hh][0], fmaf(l1, qs[hh][1], fmaf(l2, qs[hh][2], l3 * qs[hh][3])));
    #pragma unroll
    for (int sft = 32; sft; sft >>= 1){
      #pragma unroll
      for (int hh = 0; hh < NH; hh++) p[hh] += __shfl_down(p[hh], sft);
    }
    if (lane == 0){
      #pragma unroll
      for (int hh = 0; hh < NH; hh++) pl[wid][hh] = p[hh];
    }
    __syncthreads();
    if (t < NH){
      float v = pl[0][t] + pl[1][t] + pl[2][t] + pl[3][t];
      const float* wb = wbias + t * 40;
      float bb = 0.f;
      #pragma unroll
      for (int j = 0; j < 16; j++) bb = fmaf(rbf[(size_t)n * 16 + j], wb[j], bb);
      #pragma unroll
      for (int j = 0; j < 4; j++)  bb = fmaf(seqsep[(size_t)n * 4 + j], wb[16 + j], bb);
      #pragma unroll
      for (int j = 0; j < 20; j++) bb = fmaf(extra[(size_t)n * DEX + j], wb[20 + j], bb);
      logits[(size_t)t * NN + n] = v + bb;
    }
    __syncthreads();
  }
}

// ---------- per-head softmax stats: m, s ----------
__global__ void k_smstats(const float* __restrict__ logits, float* __restrict__ ms){
  const int hh = blockIdx.x, t = threadIdx.x, lane = t & 63, wid = t >> 6;
  __shared__ float red[16];
  __shared__ float bcast;
  const float* lp = logits + (size_t)hh * NN;
  float m = -3.0e38f;
  for (int n = t; n < NN; n += 1024) m = fmaxf(m, lp[n]);
  #pragma unroll
  for (int s = 32; s; s >>= 1) m = fmaxf(m, __shfl_down(m, s));
  if (lane == 0) red[wid] = m;
  __syncthreads();
  if (t == 0){
    float mm = red[0];
    #pragma unroll
    for (int i = 1; i < 16; i++) mm = fmaxf(mm, red[i]);
    bcast = mm;
  }
  __syncthreads();
  m = bcast;
  float s = 0.f;
  for (int n = t; n < NN; n += 1024) s += __expf(lp[n] - m);
  s = wred(s);
  if (lane == 0) red[wid] = s;
  __syncthreads();
  if (t == 0){
    float sv = 0.f;
    #pragma unroll
    for (int i = 0; i < 16; i++) sv += red[i];
    ms[hh] = m; ms[16 + hh] = sv;
  }
}

// ---------- u partials: upart[b,hh,d] = sum_rows exp(logit-m) * LN(h) ----------
#define UB 512
__global__ void k_upart(const unsigned short* __restrict__ hbf, const float* __restrict__ meanb,
                        const float* __restrict__ rstdb, const float* __restrict__ aw,
                        const float* __restrict__ ab, const float* __restrict__ logits,
                        const float* __restrict__ ms, float* __restrict__ upart){
  const int t = threadIdx.x, bb = blockIdx.x;
  const float4 w  = *(const float4*)(aw + t * 4);
  const float4 bv = *(const float4*)(ab + t * 4);
  float mh[NH];
  #pragma unroll
  for (int hh = 0; hh < NH; hh++) mh[hh] = ms[hh];
  float acc[NH][4];
  #pragma unroll
  for (int hh = 0; hh < NH; hh++){ acc[hh][0] = 0.f; acc[hh][1] = 0.f; acc[hh][2] = 0.f; acc[hh][3] = 0.f; }
  #pragma unroll 2
  for (int r = 0; r < NN / UB; r++){
    const int n = bb * (NN / UB) + r;
    const float mean = meanb[n], rstd = rstdb[n];
    const ushort4 hb = *(const ushort4*)(hbf + (size_t)n * DM + t * 4);
    const float l0 = (bf2f(hb.x) - mean) * rstd * w.x + bv.x;
    const float l1 = (bf2f(hb.y) - mean) * rstd * w.y + bv.y;
    const float l2 = (bf2f(hb.z) - mean) * rstd * w.z + bv.z;
    const float l3 = (bf2f(hb.w) - mean) * rstd * w.w + bv.w;
    #pragma unroll
    for (int hh = 0; hh < NH; hh++){
      const float e = __expf(logits[(size_t)hh * NN + n] - mh[hh]);
      acc[hh][0] = fmaf(e, l0, acc[hh][0]);
      acc[hh][1] = fmaf(e, l1, acc[hh][1]);
      acc[hh][2] = fmaf(e, l2, acc[hh][2]);
      acc[hh][3] = fmaf(e, l3, acc[hh][3]);
    }
  }
  #pragma unroll
  for (int hh = 0; hh < NH; hh++){
    float4 o; o.x = acc[hh][0]; o.y = acc[hh][1]; o.z = acc[hh][2]; o.w = acc[hh][3];
    *(float4*)(upart + ((size_t)bb * NH + hh) * DM + t * 4) = o;
  }
}

// ---------- reduce partials, normalize by s ----------
__global__ void k_ureduce(const float* __restrict__ upart, const float* __restrict__ ms,
                          float* __restrict__ u){
  const int idx = blockIdx.x * 256 + threadIdx.x;   // 0..16383
  const int hh = idx >> 10;
  float s = 0.f;
  for (int b = 0; b < UB; b++) s += upart[(size_t)b * (NH * DM) + idx];
  u[idx] = s / ms[16 + hh];
}

// ---------- out_center[o] = u[head(o),:] . Wv[o,:] ----------
__global__ void k_oc(const float* __restrict__ u, const float* __restrict__ Wv,
                     float* __restrict__ oc){
  int lane = threadIdx.x & 63, wid = threadIdx.x >> 6;
  #pragma unroll
  for (int oi = 0; oi < 4; oi++){
    int o = blockIdx.x * 16 + wid * 4 + oi;
    const float* ur = u + (size_t)(o >> 6) * DM;
    const float* wr = Wv + (size_t)o * DM;
    float a = 0.f;
    #pragma unroll
    for (int j = 0; j < 16; j++) a = fmaf(ur[lane + 64 * j], wr[lane + 64 * j], a);
    a = wred(a);
    if (lane == 0) oc[o] = a;
  }
}

// ---------- hcnew[o] = h[c,o] + 0.5 * oc . Wo[o,:] ----------
__global__ void k_delta(const float* __restrict__ oc, const float* __restrict__ Wo,
                        const float* __restrict__ h, const int* __restrict__ cidx,
                        float* __restrict__ hcnew){
  int lane = threadIdx.x & 63, wid = threadIdx.x >> 6;
  int c = *cidx;
  float ov[16];
  #pragma unroll
  for (int j = 0; j < 16; j++) ov[j] = oc[lane + 64 * j];
  #pragma unroll
  for (int oi = 0; oi < 4; oi++){
    int o = blockIdx.x * 16 + wid * 4 + oi;
    const float* wr = Wo + (size_t)o * DM;
    float a = 0.f;
    #pragma unroll
    for (int j = 0; j < 16; j++) a = fmaf(ov[j], wr[lane + 64 * j], a);
    a = wred(a);
    if (lane == 0) hcnew[o] = h[(size_t)c * DM + o] + 0.5f * a;
  }
}

// ---------- rank-1 column biases: gbtot/fbtot ----------
__global__ void k_gbfb(const float* __restrict__ hcnew, const float* __restrict__ gateW,
                       const float* __restrict__ gateB, const float* __restrict__ fuseW1,
                       const float* __restrict__ fuseB1, float* __restrict__ gbtot,
                       float* __restrict__ fbtot){
  int lane = threadIdx.x & 63, wid = threadIdx.x >> 6;
  float hv[16];
  #pragma unroll
  for (int j = 0; j < 16; j++) hv[j] = hcnew[lane + 64 * j];
  #pragma unroll
  for (int oi = 0; oi < 4; oi++){
    int o = blockIdx.x * 16 + wid * 4 + oi;
    const float* gr = gateW + (size_t)o * 2048 + 1024;
    const float* fr = fuseW1 + (size_t)o * 2048 + 1024;
    float ga = 0.f, fa = 0.f;
    #pragma unroll
    for (int j = 0; j < 16; j++){
      ga = fmaf(hv[j], gr[lane + 64 * j], ga);
      fa = fmaf(hv[j], fr[lane + 64 * j], fa);
    }
    ga = wred(ga); fa = wred(fa);
    if (lane == 0){ gbtot[o] = ga + gateB[o]; fbtot[o] = fa + fuseB1[o]; }
  }
}

// ---------- MFMA GEMM, 256x256 tile, BK=64, 8-phase counted-vmcnt schedule ----------
// 512 thr = 8 waves (2M x 4N); per-wave output 128x64; LDS = 2buf x 2half x (128x64) x {A,B} = 128 KiB.
// Stage ledger (iter i, k0=2i): P1:A0(k0+1)->b1  P2:A1(k0+1)->b1  P3:B0(k0+2)->b0  P4:B1(k0+2)->b0 [vmcnt4]
//                               P5:A0(k0+2)->b0  P6:A1(k0+2)->b0  P7:B0(k0+3)->b1  P8:B1(k0+3)->b1 [vmcnt4]
// vmcnt(4): 4 newest loads (= last 2 stages) may stay in flight; all data read next phase has landed.
// Every stage targets a region whose last ds_read was >=1 end-of-phase barrier earlier (no overwrite race).
// Swizzle: LDS[r][ch16] = G[r][ch16 ^ (r&7)]; same XOR on ds_read (2 lanes/bank = free).
#define BM 256
#define BK 64
#define H128 ((size_t)128 * DM)
#define GLL16(gp, lp) __builtin_amdgcn_global_load_lds((const __attribute__((address_space(1))) void*)(gp), (__attribute__((address_space(3))) void*)(lp), 16, 0, 0)
#define MFMA16(a, b, c) __builtin_amdgcn_mfma_f32_16x16x32_bf16(a, b, c, 0, 0, 0)

#define PHASE(BUF, Q, STG, STL, STK, DOVM) do {                                        \
    if ((Q) == 0){                                                                     \
      _Pragma("unroll")                                                                \
      for (int nj = 0; nj < 4; nj++){                                                  \
        bq[nj][0] = *(const bf16x8*)(lB + (BUF)*16384 + bBase + nj*1024 + kOff0);      \
        bq[nj][1] = *(const bf16x8*)(lB + (BUF)*16384 + bBase + nj*1024 + kOff1);      \
      }                                                                                \
    }                                                                                  \
    bf16x8 a00 = *(const bf16x8*)(lA + (BUF)*16384 + aBase + (2*(Q))*1024   + kOff0);  \
    bf16x8 a01 = *(const bf16x8*)(lA + (BUF)*16384 + aBase + (2*(Q))*1024   + kOff1);  \
    bf16x8 a10 = *(const bf16x8*)(lA + (BUF)*16384 + aBase + (2*(Q)+1)*1024 + kOff0);  \
    bf16x8 a11 = *(const bf16x8*)(lA + (BUF)*16384 + aBase + (2*(Q)+1)*1024 + kOff1);  \
    stage(STG, STL, STK);                                                              \
    __builtin_amdgcn_s_barrier();                                                      \
    asm volatile("s_waitcnt lgkmcnt(0)" ::: "memory");                                 \
    __builtin_amdgcn_sched_barrier(0);                                                 \
    __builtin_amdgcn_s_setprio(1);                                                     \
    _Pragma("unroll")                                                                  \
    for (int nj = 0; nj < 4; nj++){                                                    \
      acc[2*(Q)][nj]   = MFMA16(a00, bq[nj][0], acc[2*(Q)][nj]);                       \
      acc[2*(Q)][nj]   = MFMA16(a01, bq[nj][1], acc[2*(Q)][nj]);                       \
      acc[2*(Q)+1][nj] = MFMA16(a10, bq[nj][0], acc[2*(Q)+1][nj]);                     \
      acc[2*(Q)+1][nj] = MFMA16(a11, bq[nj][1], acc[2*(Q)+1][nj]);                     \
    }                                                                                  \
    __builtin_amdgcn_s_setprio(0);                                                     \
    if (DOVM){ asm volatile("s_waitcnt vmcnt(4)" ::: "memory"); }                      \
    __builtin_amdgcn_s_barrier();                                                      \
  } while (0)

template<int MODE>
__launch_bounds__(512, 2)
__global__ void k_gemm(const unsigned short* __restrict__ A, const unsigned short* __restrict__ B,
                       const float* __restrict__ bias0, const float* __restrict__ bias1,
                       const float* __restrict__ hsrc, const unsigned short* __restrict__ gate,
                       unsigned short* __restrict__ og, unsigned short* __restrict__ ot,
                       float* __restrict__ of){
  __shared__ __attribute__((aligned(16))) unsigned short lA[32768];
  __shared__ __attribute__((aligned(16))) unsigned short lB[32768];
  const int NWG = (MODE == 0) ? 2048 : 1024;
  const int NYT = (MODE == 0) ? 8 : 4;
  const int bid = blockIdx.x;
  const int remap = (bid & 7) * (NWG >> 3) + (bid >> 3);   // XCD-chunk swizzle (bijective)
  const int m0 = (remap / NYT) * BM, n0 = (remap % NYT) * BM;

  const int tid = threadIdx.x, lane = tid & 63, w = tid >> 6;
  const int wm = w >> 2, wn = w & 3;

  f32x4 acc[8][4];
  #pragma unroll
  for (int i = 0; i < 8; i++){
    #pragma unroll
    for (int j = 0; j < 4; j++){ acc[i][j][0] = 0.f; acc[i][j][1] = 0.f; acc[i][j][2] = 0.f; acc[i][j][3] = 0.f; }
  }

  // staging invariants: wave w stages rows w*16..w*16+15 of a 128-row half (2 loads)
  const int ln3 = lane >> 3;
  const size_t stRow0 = (size_t)(w * 16 + ln3);
  const int sxor = ((lane & 7) ^ ln3) * 8;            // pre-swizzled source chunk
  const size_t srcOff0 = stRow0 * DM + sxor;
  const size_t srcOff1 = (stRow0 + 8) * DM + sxor;
  const int dst0 = w * 1024 + lane * 8;               // wave-uniform base + lane*16B
  const int dst1 = dst0 + 512;

  const unsigned short* gA = A + (size_t)m0 * DM;
  const unsigned short* gB = B + (size_t)n0 * DM;

  auto stage = [&](const unsigned short* g, unsigned short* ldsr, int kt){
    GLL16(g + srcOff0 + kt * 64, ldsr + dst0);
    GLL16(g + srcOff1 + kt * 64, ldsr + dst1);
  };

  // read invariants
  const int fr = lane & 15;
  const int kq = lane >> 4;
  const int kOff0 = ((kq)     ^ (lane & 7)) * 8;
  const int kOff1 = ((4 + kq) ^ (lane & 7)) * 8;
  const int aBase = wm * 8192 + fr * 64;
  const int bBase = (wn >> 1) * 8192 + ((wn & 1) * 64 + fr) * 64;

  bf16x8 bq[4][2];

  // prologue: buf0 <- A(0),B(0); buf1 <- B(1). vmcnt(4): B(1)'s 4 loads may remain.
  stage(gA,        lA,                0);
  stage(gA + H128, lA + 8192,         0);
  stage(gB,        lB,                0);
  stage(gB + H128, lB + 8192,         0);
  stage(gB,        lB + 16384,        1);
  stage(gB + H128, lB + 16384 + 8192, 1);
  asm volatile("s_waitcnt vmcnt(4)" ::: "memory");
  __builtin_amdgcn_s_barrier();

  #pragma unroll 1
  for (int i = 0; i < 8; i++){
    const int k0 = 2 * i;
    PHASE(0, 0, gA,        lA + 16384,        k0 + 1,        false);
    PHASE(0, 1, gA + H128, lA + 16384 + 8192, k0 + 1,        false);
    PHASE(0, 2, gB,        lB,                (k0 + 2) & 15, false);
    PHASE(0, 3, gB + H128, lB + 8192,         (k0 + 2) & 15, true);
    PHASE(1, 0, gA,        lA,                (k0 + 2) & 15, false);
    PHASE(1, 1, gA + H128, lA + 8192,         (k0 + 2) & 15, false);
    PHASE(1, 2, gB,        lB + 16384,        (k0 + 3) & 15, false);
    PHASE(1, 3, gB + H128, lB + 16384 + 8192, (k0 + 3) & 15, true);
  }

  const int r0 = kq * 4;
  #pragma unroll
  for (int mi = 0; mi < 8; mi++){
    #pragma unroll
    for (int nj = 0; nj < 4; nj++){
      const int gmb = m0 + wm * 128 + mi * 16 + r0;
      const int gn  = n0 + wn * 64 + nj * 16 + fr;
      #pragma unroll
      for (int r = 0; r < 4; r++){
        const int gm = gmb + r;
        const float x = acc[mi][nj][r];
        if (MODE == 0){
          if (gn < 1024){
            const float v = x + bias0[gn];
            og[(size_t)gm * DM + gn] = f2bf(1.0f / (1.0f + __expf(-v)));
          } else {
            const float v = x + bias1[gn - 1024];
            ot[(size_t)gm * DM + (gn - 1024)] = f2bf(v / (1.0f + __expf(-v)));
          }
        } else {
          const float v = x + bias0[gn];
          const float g = bf2f(gate[(size_t)gm * DM + gn]);
          of[(size_t)gm * DM + gn] = hsrc[(size_t)gm * DM + gn] + 0.5f * g * v;
        }
      }
    }
  }
}

// ---------- overwrite center row ----------
__global__ void k_fixc(const float* __restrict__ hcnew, const int* __restrict__ cidx,
                       float* __restrict__ out){
  int t = threadIdx.x;
  int c = *cidx;
  out[(size_t)c * DM + t] = hcnew[t];
}

extern "C" void kernel_launch(void* const* d_in, const int* in_sizes, int n_in,
                              void* d_out, int out_size, void* d_ws, size_t ws_size,
                              hipStream_t stream){
  const float* h      = (const float*)d_in[0];
  const float* rbf    = (const float*)d_in[1];
  const float* seqsep = (const float*)d_in[2];
  const float* localb = (const float*)d_in[3];
  const float* ncw    = (const float*)d_in[4];
  const float* ncb    = (const float*)d_in[5];
  const float* naw    = (const float*)d_in[6];
  const float* nab    = (const float*)d_in[7];
  const float* Wq     = (const float*)d_in[8];
  const float* Wk     = (const float*)d_in[9];
  const float* Wv     = (const float*)d_in[10];
  const float* Wo     = (const float*)d_in[11];
  const float* Wbias  = (const float*)d_in[12];
  const float* gateW  = (const float*)d_in[13];
  const float* gateB  = (const float*)d_in[14];
  const float* fuseW1 = (const float*)d_in[15];
  const float* fuseB1 = (const float*)d_in[16];
  const float* fuseW2 = (const float*)d_in[17];
  const float* fuseB2 = (const float*)d_in[18];
  const int*   nbr    = (const int*)d_in[19];
  const int*   cidx   = (const int*)d_in[20];
  float* out = (float*)d_out;

  char* p = (char*)d_ws;
  auto alloc = [&](size_t nb){ char* r = p; p += (nb + 255) & ~(size_t)255; return r; };
  float* extra  = (float*)alloc((size_t)NN * DEX * 4);
  float* logits = (float*)alloc((size_t)NH * NN * 4);
  float* meanb  = (float*)alloc((size_t)NN * 4);
  float* rstdb  = (float*)alloc((size_t)NN * 4);
  float* ms     = (float*)alloc(32 * 4);
  float* qkt    = (float*)alloc(NH * DM * 4);
  float* u      = (float*)alloc(NH * DM * 4);
  float* hcln   = (float*)alloc(DM * 4);
  float* qv     = (float*)alloc(DM * 4);
  float* oc     = (float*)alloc(DM * 4);
  float* hcnew  = (float*)alloc(DM * 4);
  float* gbtot  = (float*)alloc(DM * 4);
  float* fbtot  = (float*)alloc(DM * 4);
  float* upart  = (float*)alloc((size_t)UB * NH * DM * 4);
  unsigned short* Wcomb = (unsigned short*)alloc((size_t)2048 * 1024 * 2);
  unsigned short* W2b   = (unsigned short*)alloc((size_t)1024 * 1024 * 2);
  unsigned short* hbf   = (unsigned short*)alloc((size_t)NN * DM * 2);
  unsigned short* gateb = (unsigned short*)alloc((size_t)NN * DM * 2);
  unsigned short* t1    = (unsigned short*)alloc((size_t)NN * DM * 2);
  if ((size_t)(p - (char*)d_ws) > ws_size) return;  // clean fail instead of corruption

  hipMemsetAsync(extra, 0, (size_t)NN * DEX * 4, stream);
  k_scatter<<<(KNB * DEX + 255) / 256, 256, 0, stream>>>(localb, nbr, extra);
  k_convw<<<(3 * 1024 * 1024) / 256, 256, 0, stream>>>(gateW, fuseW1, fuseW2, Wcomb, W2b);
  k_cln<<<1, 256, 0, stream>>>(h, cidx, ncw, ncb, hcln);
  k_q<<<64, 256, 0, stream>>>(hcln, Wq, qv);
  k_qkt<<<64, 256, 0, stream>>>(qv, Wk, qkt);
  k_rowpass<<<NN / 8, 256, 0, stream>>>(h, naw, nab, rbf, seqsep, extra, Wbias, qkt,
                                        logits, meanb, rstdb, hbf);
  k_smstats<<<16, 1024, 0, stream>>>(logits, ms);
  k_upart<<<UB, 256, 0, stream>>>(hbf, meanb, rstdb, naw, nab, logits, ms, upart);
  k_ureduce<<<64, 256, 0, stream>>>(upart, ms, u);
  k_oc<<<64, 256, 0, stream>>>(u, Wv, oc);
  k_delta<<<64, 256, 0, stream>>>(oc, Wo, h, cidx, hcnew);
  k_gbfb<<<64, 256, 0, stream>>>(hcnew, gateW, gateB, fuseW1, fuseB1, gbtot, fbtot);
  k_gemm<0><<<2048, 512, 0, stream>>>(hbf, Wcomb, gbtot, fbtot, nullptr, nullptr, gateb, t1, nullptr);
  k_gemm<1><<<1024, 512, 0, stream>>>(t1, W2b, fuseB2, nullptr, h, gateb, nullptr, nullptr, out);
  k_fixc<<<1, 1024, 0, stream>>>(hcnew, cidx, out);
}

// Round 5
// 1267.866 us; speedup vs baseline: 1.2110x; 1.0044x over previous
//
#include <hip/hip_runtime.h>
#include <hip/hip_bf16.h>

#define NN 65536
#define DM 1024
#define NH 16
#define KNB 4096
#define DEX 20
#define EPSV 1e-5f

typedef __attribute__((ext_vector_type(8))) short bf16x8;
typedef __attribute__((ext_vector_type(4))) float f32x4;

__device__ __forceinline__ unsigned short f2bf(float f){
  unsigned u = __builtin_bit_cast(unsigned, f);
  u += 0x7fffu + ((u >> 16) & 1u);
  return (unsigned short)(u >> 16);
}
__device__ __forceinline__ float bf2f(unsigned short s){
  return __builtin_bit_cast(float, ((unsigned)s) << 16);
}
__device__ __forceinline__ float wred(float v){
  #pragma unroll
  for (int s = 32; s; s >>= 1) v += __shfl_down(v, s);
  return v;
}

// ---------- scatter local_bias rows into extra (N x 20); extra pre-zeroed ----------
__global__ void k_scatter(const float* __restrict__ lb, const int* __restrict__ nidx,
                          float* __restrict__ extra){
  int i = blockIdx.x * 256 + threadIdx.x;
  if (i < KNB * DEX){
    int j = i / DEX, col = i - j * DEX;
    extra[(size_t)nidx[j] * DEX + col] = lb[i];
  }
}

// ---------- convert MLP weights to bf16: Wcomb (2048x1024) + W2b (1024x1024) ----------
__global__ void k_convw(const float* __restrict__ gateW, const float* __restrict__ fuseW1,
                        const float* __restrict__ fuseW2,
                        unsigned short* __restrict__ Wcomb, unsigned short* __restrict__ W2b){
  int i = blockIdx.x * 256 + threadIdx.x;
  if (i < 2048 * 1024){
    int o = i >> 10, d = i & 1023;
    float v = (o < 1024) ? gateW[(size_t)o * 2048 + d] : fuseW1[(size_t)(o - 1024) * 2048 + d];
    Wcomb[i] = f2bf(v);
  } else {
    int j = i - 2048 * 1024;
    W2b[j] = f2bf(fuseW2[j]);
  }
}

// ---------- LN of center row (norm_c) -> hcln[1024] ----------
__global__ void k_cln(const float* __restrict__ h, const int* __restrict__ cidx,
                      const float* __restrict__ cw, const float* __restrict__ cb,
                      float* __restrict__ hcln){
  int t = threadIdx.x, lane = t & 63, wid = t >> 6;
  int c = *cidx;
  const float4 x = *(const float4*)(h + (size_t)c * DM + t * 4);
  float s  = x.x + x.y + x.z + x.w;
  float ss = x.x * x.x + x.y * x.y + x.z * x.z + x.w * x.w;
  __shared__ float rs[4], rq[4];
  s = wred(s); ss = wred(ss);
  if (lane == 0){ rs[wid] = s; rq[wid] = ss; }
  __syncthreads();
  float mean = (rs[0] + rs[1] + rs[2] + rs[3]) * (1.0f / DM);
  float var  = (rq[0] + rq[1] + rq[2] + rq[3]) * (1.0f / DM) - mean * mean;
  float rstd = rsqrtf(var + EPSV);
  const float4 w = *(const float4*)(cw + t * 4);
  const float4 b = *(const float4*)(cb + t * 4);
  float4 o;
  o.x = (x.x - mean) * rstd * w.x + b.x;
  o.y = (x.y - mean) * rstd * w.y + b.y;
  o.z = (x.z - mean) * rstd * w.z + b.z;
  o.w = (x.w - mean) * rstd * w.w + b.w;
  *(float4*)(hcln + t * 4) = o;
}

// ---------- q[o] = hcln . Wq[o,:]   (64 blocks x 256; wave-split-K, coalesced) ----------
__global__ void k_q(const float* __restrict__ hcln, const float* __restrict__ Wq,
                    float* __restrict__ q){
  int lane = threadIdx.x & 63, wid = threadIdx.x >> 6;
  float hv[16];
  #pragma unroll
  for (int j = 0; j < 16; j++) hv[j] = hcln[lane + 64 * j];
  #pragma unroll
  for (int oi = 0; oi < 4; oi++){
    int o = blockIdx.x * 16 + wid * 4 + oi;
    const float* wr = Wq + (size_t)o * DM;
    float a = 0.f;
    #pragma unroll
    for (int j = 0; j < 16; j++) a = fmaf(hv[j], wr[lane + 64 * j], a);
    a = wred(a);
    if (lane == 0) q[o] = a;
  }
}

// ---------- qkt[hh,i] = (sum_d q[hh*64+d] * Wk[hh*64+d, i]) / 8 ----------
__global__ void k_qkt(const float* __restrict__ q, const float* __restrict__ Wk,
                      float* __restrict__ qkt){
  int idx = blockIdx.x * 256 + threadIdx.x;   // 0..16383
  int hh = idx >> 10, i = idx & 1023;
  float a = 0.f;
  #pragma unroll 8
  for (int d = 0; d < 64; d++) a = fmaf(q[hh * 64 + d], Wk[(size_t)(hh * 64 + d) * DM + i], a);
  qkt[idx] = a * 0.125f;
}

// ---------- head constants: c12[h] = sum_d aw[d]*qkt[h][d]; c12[16+h] = sum_d ab[d]*qkt[h][d] ----------
__global__ void k_c12(const float* __restrict__ qkt, const float* __restrict__ aw,
                      const float* __restrict__ ab, float* __restrict__ c12){
  const int hh = blockIdx.x >> 1, which = blockIdx.x & 1, lane = threadIdx.x;
  const float* src = which ? ab : aw;
  float a = 0.f;
  #pragma unroll
  for (int j = 0; j < 16; j++) a = fmaf(src[lane + 64 * j], qkt[hh * DM + lane + 64 * j], a);
  a = wred(a);
  if (lane == 0) c12[which * NH + hh] = a;
}

// ---------- big row pass: LN stats, logits (16 heads), bias, h->bf16 (1 barrier/row) ----------
// logit_h = rstd*S1_h - rstd*mean*C1_h + C2_h,  S1_h = sum_d x_d*aw_d*q_hd
__global__ void k_rowpass(const float* __restrict__ h, const float* __restrict__ aw,
                          const float* __restrict__ ab, const float* __restrict__ rbf,
                          const float* __restrict__ seqsep, const float* __restrict__ extra,
                          const float* __restrict__ wbias, const float* __restrict__ qkt,
                          const float* __restrict__ c12,
                          float* __restrict__ logits, float* __restrict__ meanb,
                          float* __restrict__ rstdb, unsigned short* __restrict__ hbf){
  const int t = threadIdx.x, lane = t & 63, wid = t >> 6;
  float qs[NH][4];
  #pragma unroll
  for (int hh = 0; hh < NH; hh++){
    const float4 v = *(const float4*)(qkt + hh * DM + t * 4);
    qs[hh][0] = v.x; qs[hh][1] = v.y; qs[hh][2] = v.z; qs[hh][3] = v.w;
  }
  const float4 w = *(const float4*)(aw + t * 4);
  __shared__ float red[2][4][NH + 2];
  for (int r = 0; r < 8; r++){
    const int n = blockIdx.x * 8 + r;
    const float4 x = *(const float4*)(h + (size_t)n * DM + t * 4);
    float s  = x.x + x.y + x.z + x.w;
    float ss = x.x * x.x + x.y * x.y + x.z * x.z + x.w * x.w;
    ushort4 hb;
    hb.x = f2bf(x.x); hb.y = f2bf(x.y); hb.z = f2bf(x.z); hb.w = f2bf(x.w);
    *(ushort4*)(hbf + (size_t)n * DM + t * 4) = hb;
    const float xw0 = x.x * w.x, xw1 = x.y * w.y, xw2 = x.z * w.z, xw3 = x.w * w.w;
    float p[NH];
    #pragma unroll
    for (int hh = 0; hh < NH; hh++)
      p[hh] = fmaf(xw0, qs[hh][0], fmaf(xw1, qs[hh][1], fmaf(xw2, qs[hh][2], xw3 * qs[hh][3])));
    s = wred(s); ss = wred(ss);
    #pragma unroll
    for (int hh = 0; hh < NH; hh++) p[hh] = wred(p[hh]);
    if (lane == 0){
      #pragma unroll
      for (int hh = 0; hh < NH; hh++) red[r & 1][wid][hh] = p[hh];
      red[r & 1][wid][NH] = s; red[r & 1][wid][NH + 1] = ss;
    }
    __syncthreads();
    if (t < NH){
      const float sm = red[r & 1][0][NH] + red[r & 1][1][NH] + red[r & 1][2][NH] + red[r & 1][3][NH];
      const float sq = red[r & 1][0][NH + 1] + red[r & 1][1][NH + 1] + red[r & 1][2][NH + 1] + red[r & 1][3][NH + 1];
      const float mean = sm * (1.0f / DM);
      const float var  = sq * (1.0f / DM) - mean * mean;
      const float rstd = rsqrtf(var + EPSV);
      if (t == 0){ meanb[n] = mean; rstdb[n] = rstd; }
      const float S1 = red[r & 1][0][t] + red[r & 1][1][t] + red[r & 1][2][t] + red[r & 1][3][t];
      const float* wb = wbias + t * 40;
      float bb = 0.f;
      #pragma unroll
      for (int j = 0; j < 16; j++) bb = fmaf(rbf[(size_t)n * 16 + j], wb[j], bb);
      #pragma unroll
      for (int j = 0; j < 4; j++)  bb = fmaf(seqsep[(size_t)n * 4 + j], wb[16 + j], bb);
      #pragma unroll
      for (int j = 0; j < 20; j++) bb = fmaf(extra[(size_t)n * DEX + j], wb[20 + j], bb);
      logits[(size_t)t * NN + n] = rstd * S1 - rstd * mean * c12[t] + c12[NH + t] + bb;
    }
  }
}

// ---------- per-head softmax stats: m, s ----------
__global__ void k_smstats(const float* __restrict__ logits, float* __restrict__ ms){
  const int hh = blockIdx.x, t = threadIdx.x, lane = t & 63, wid = t >> 6;
  __shared__ float red[16];
  __shared__ float bcast;
  const float* lp = logits + (size_t)hh * NN;
  float m = -3.0e38f;
  for (int n = t; n < NN; n += 1024) m = fmaxf(m, lp[n]);
  #pragma unroll
  for (int s = 32; s; s >>= 1) m = fmaxf(m, __shfl_down(m, s));
  if (lane == 0) red[wid] = m;
  __syncthreads();
  if (t == 0){
    float mm = red[0];
    #pragma unroll
    for (int i = 1; i < 16; i++) mm = fmaxf(mm, red[i]);
    bcast = mm;
  }
  __syncthreads();
  m = bcast;
  float s = 0.f;
  for (int n = t; n < NN; n += 1024) s += __expf(lp[n] - m);
  s = wred(s);
  if (lane == 0) red[wid] = s;
  __syncthreads();
  if (t == 0){
    float sv = 0.f;
    #pragma unroll
    for (int i = 0; i < 16; i++) sv += red[i];
    ms[hh] = m; ms[16 + hh] = sv;
  }
}

// ---------- u partials: upart[b,hh,d] = sum_rows exp(logit-m) * LN(h) ----------
#define UB 512
__global__ void k_upart(const unsigned short* __restrict__ hbf, const float* __restrict__ meanb,
                        const float* __restrict__ rstdb, const float* __restrict__ aw,
                        const float* __restrict__ ab, const float* __restrict__ logits,
                        const float* __restrict__ ms, float* __restrict__ upart){
  const int t = threadIdx.x, bb = blockIdx.x;
  const float4 w  = *(const float4*)(aw + t * 4);
  const float4 bv = *(const float4*)(ab + t * 4);
  float mh[NH];
  #pragma unroll
  for (int hh = 0; hh < NH; hh++) mh[hh] = ms[hh];
  float acc[NH][4];
  #pragma unroll
  for (int hh = 0; hh < NH; hh++){ acc[hh][0] = 0.f; acc[hh][1] = 0.f; acc[hh][2] = 0.f; acc[hh][3] = 0.f; }
  #pragma unroll 2
  for (int r = 0; r < NN / UB; r++){
    const int n = bb * (NN / UB) + r;
    const float mean = meanb[n], rstd = rstdb[n];
    const ushort4 hb = *(const ushort4*)(hbf + (size_t)n * DM + t * 4);
    const float l0 = (bf2f(hb.x) - mean) * rstd * w.x + bv.x;
    const float l1 = (bf2f(hb.y) - mean) * rstd * w.y + bv.y;
    const float l2 = (bf2f(hb.z) - mean) * rstd * w.z + bv.z;
    const float l3 = (bf2f(hb.w) - mean) * rstd * w.w + bv.w;
    #pragma unroll
    for (int hh = 0; hh < NH; hh++){
      const float e = __expf(logits[(size_t)hh * NN + n] - mh[hh]);
      acc[hh][0] = fmaf(e, l0, acc[hh][0]);
      acc[hh][1] = fmaf(e, l1, acc[hh][1]);
      acc[hh][2] = fmaf(e, l2, acc[hh][2]);
      acc[hh][3] = fmaf(e, l3, acc[hh][3]);
    }
  }
  #pragma unroll
  for (int hh = 0; hh < NH; hh++){
    float4 o; o.x = acc[hh][0]; o.y = acc[hh][1]; o.z = acc[hh][2]; o.w = acc[hh][3];
    *(float4*)(upart + ((size_t)bb * NH + hh) * DM + t * 4) = o;
  }
}

// ---------- reduce partials, normalize by s ----------
__global__ void k_ureduce(const float* __restrict__ upart, const float* __restrict__ ms,
                          float* __restrict__ u){
  const int idx = blockIdx.x * 256 + threadIdx.x;   // 0..16383
  const int hh = idx >> 10;
  float s = 0.f;
  for (int b = 0; b < UB; b++) s += upart[(size_t)b * (NH * DM) + idx];
  u[idx] = s / ms[16 + hh];
}

// ---------- out_center[o] = u[head(o),:] . Wv[o,:] ----------
__global__ void k_oc(const float* __restrict__ u, const float* __restrict__ Wv,
                     float* __restrict__ oc){
  int lane = threadIdx.x & 63, wid = threadIdx.x >> 6;
  #pragma unroll
  for (int oi = 0; oi < 4; oi++){
    int o = blockIdx.x * 16 + wid * 4 + oi;
    const float* ur = u + (size_t)(o >> 6) * DM;
    const float* wr = Wv + (size_t)o * DM;
    float a = 0.f;
    #pragma unroll
    for (int j = 0; j < 16; j++) a = fmaf(ur[lane + 64 * j], wr[lane + 64 * j], a);
    a = wred(a);
    if (lane == 0) oc[o] = a;
  }
}

// ---------- hcnew[o] = h[c,o] + 0.5 * oc . Wo[o,:] ----------
__global__ void k_delta(const float* __restrict__ oc, const float* __restrict__ Wo,
                        const float* __restrict__ h, const int* __restrict__ cidx,
                        float* __restrict__ hcnew){
  int lane = threadIdx.x & 63, wid = threadIdx.x >> 6;
  int c = *cidx;
  float ov[16];
  #pragma unroll
  for (int j = 0; j < 16; j++) ov[j] = oc[lane + 64 * j];
  #pragma unroll
  for (int oi = 0; oi < 4; oi++){
    int o = blockIdx.x * 16 + wid * 4 + oi;
    const float* wr = Wo + (size_t)o * DM;
    float a = 0.f;
    #pragma unroll
    for (int j = 0; j < 16; j++) a = fmaf(ov[j], wr[lane + 64 * j], a);
    a = wred(a);
    if (lane == 0) hcnew[o] = h[(size_t)c * DM + o] + 0.5f * a;
  }
}

// ---------- rank-1 column biases: gbtot/fbtot ----------
__global__ void k_gbfb(const float* __restrict__ hcnew, const float* __restrict__ gateW,
                       const float* __restrict__ gateB, const float* __restrict__ fuseW1,
                       const float* __restrict__ fuseB1, float* __restrict__ gbtot,
                       float* __restrict__ fbtot){
  int lane = threadIdx.x & 63, wid = threadIdx.x >> 6;
  float hv[16];
  #pragma unroll
  for (int j = 0; j < 16; j++) hv[j] = hcnew[lane + 64 * j];
  #pragma unroll
  for (int oi = 0; oi < 4; oi++){
    int o = blockIdx.x * 16 + wid * 4 + oi;
    const float* gr = gateW + (size_t)o * 2048 + 1024;
    const float* fr = fuseW1 + (size_t)o * 2048 + 1024;
    float ga = 0.f, fa = 0.f;
    #pragma unroll
    for (int j = 0; j < 16; j++){
      ga = fmaf(hv[j], gr[lane + 64 * j], ga);
      fa = fmaf(hv[j], fr[lane + 64 * j], fa);
    }
    ga = wred(ga); fa = wred(fa);
    if (lane == 0){ gbtot[o] = ga + gateB[o]; fbtot[o] = fa + fuseB1[o]; }
  }
}

// ---------- MFMA GEMM, 256x256 tile, BK=64, 8-phase counted-vmcnt schedule ----------
// RAW s_barrier via inline asm (no implicit vmcnt(0) drain) — counted vmcnt(4) ledger as r4.
#define BM 256
#define BK 64
#define H128 ((size_t)128 * DM)
#define GLL16(gp, lp) __builtin_amdgcn_global_load_lds((const __attribute__((address_space(1))) void*)(gp), (__attribute__((address_space(3))) void*)(lp), 16, 0, 0)
#define MFMA16(a, b, c) __builtin_amdgcn_mfma_f32_16x16x32_bf16(a, b, c, 0, 0, 0)
#define SBAR() do { __builtin_amdgcn_sched_barrier(0); \
                    asm volatile("s_barrier" ::: "memory"); \
                    __builtin_amdgcn_sched_barrier(0); } while (0)

#define PHASE(BUF, Q, STG, STL, STK, DOVM) do {                                        \
    if ((Q) == 0){                                                                     \
      _Pragma("unroll")                                                                \
      for (int nj = 0; nj < 4; nj++){                                                  \
        bq[nj][0] = *(const bf16x8*)(lB + (BUF)*16384 + bBase + nj*1024 + kOff0);      \
        bq[nj][1] = *(const bf16x8*)(lB + (BUF)*16384 + bBase + nj*1024 + kOff1);      \
      }                                                                                \
    }                                                                                  \
    bf16x8 a00 = *(const bf16x8*)(lA + (BUF)*16384 + aBase + (2*(Q))*1024   + kOff0);  \
    bf16x8 a01 = *(const bf16x8*)(lA + (BUF)*16384 + aBase + (2*(Q))*1024   + kOff1);  \
    bf16x8 a10 = *(const bf16x8*)(lA + (BUF)*16384 + aBase + (2*(Q)+1)*1024 + kOff0);  \
    bf16x8 a11 = *(const bf16x8*)(lA + (BUF)*16384 + aBase + (2*(Q)+1)*1024 + kOff1);  \
    stage(STG, STL, STK);                                                              \
    SBAR();                                                                            \
    asm volatile("s_waitcnt lgkmcnt(0)" ::: "memory");                                 \
    __builtin_amdgcn_sched_barrier(0);                                                 \
    __builtin_amdgcn_s_setprio(1);                                                     \
    _Pragma("unroll")                                                                  \
    for (int nj = 0; nj < 4; nj++){                                                    \
      acc[2*(Q)][nj]   = MFMA16(a00, bq[nj][0], acc[2*(Q)][nj]);                       \
      acc[2*(Q)][nj]   = MFMA16(a01, bq[nj][1], acc[2*(Q)][nj]);                       \
      acc[2*(Q)+1][nj] = MFMA16(a10, bq[nj][0], acc[2*(Q)+1][nj]);                     \
      acc[2*(Q)+1][nj] = MFMA16(a11, bq[nj][1], acc[2*(Q)+1][nj]);                     \
    }                                                                                  \
    __builtin_amdgcn_s_setprio(0);                                                     \
    if (DOVM){ asm volatile("s_waitcnt vmcnt(4)" ::: "memory"); }                      \
    SBAR();                                                                            \
  } while (0)

template<int MODE>
__launch_bounds__(512, 2)
__global__ void k_gemm(const unsigned short* __restrict__ A, const unsigned short* __restrict__ B,
                       const float* __restrict__ bias0, const float* __restrict__ bias1,
                       const float* __restrict__ hsrc, const unsigned short* __restrict__ gate,
                       unsigned short* __restrict__ og, unsigned short* __restrict__ ot,
                       float* __restrict__ of){
  __shared__ __attribute__((aligned(16))) unsigned short lA[32768];
  __shared__ __attribute__((aligned(16))) unsigned short lB[32768];
  const int NWG = (MODE == 0) ? 2048 : 1024;
  const int NYT = (MODE == 0) ? 8 : 4;
  const int bid = blockIdx.x;
  const int remap = (bid & 7) * (NWG >> 3) + (bid >> 3);   // XCD-chunk swizzle (bijective)
  const int m0 = (remap / NYT) * BM, n0 = (remap % NYT) * BM;

  const int tid = threadIdx.x, lane = tid & 63, w = tid >> 6;
  const int wm = w >> 2, wn = w & 3;

  f32x4 acc[8][4];
  #pragma unroll
  for (int i = 0; i < 8; i++){
    #pragma unroll
    for (int j = 0; j < 4; j++){ acc[i][j][0] = 0.f; acc[i][j][1] = 0.f; acc[i][j][2] = 0.f; acc[i][j][3] = 0.f; }
  }

  // staging invariants: wave w stages rows w*16..w*16+15 of a 128-row half (2 loads)
  const int ln3 = lane >> 3;
  const size_t stRow0 = (size_t)(w * 16 + ln3);
  const int sxor = ((lane & 7) ^ ln3) * 8;            // pre-swizzled source chunk
  const size_t srcOff0 = stRow0 * DM + sxor;
  const size_t srcOff1 = (stRow0 + 8) * DM + sxor;
  const int dst0 = w * 1024 + lane * 8;               // wave-uniform base + lane*16B
  const int dst1 = dst0 + 512;

  const unsigned short* gA = A + (size_t)m0 * DM;
  const unsigned short* gB = B + (size_t)n0 * DM;

  auto stage = [&](const unsigned short* g, unsigned short* ldsr, int kt){
    GLL16(g + srcOff0 + kt * 64, ldsr + dst0);
    GLL16(g + srcOff1 + kt * 64, ldsr + dst1);
  };

  // read invariants
  const int fr = lane & 15;
  const int kq = lane >> 4;
  const int kOff0 = ((kq)     ^ (lane & 7)) * 8;
  const int kOff1 = ((4 + kq) ^ (lane & 7)) * 8;
  const int aBase = wm * 8192 + fr * 64;
  const int bBase = (wn >> 1) * 8192 + ((wn & 1) * 64 + fr) * 64;

  bf16x8 bq[4][2];

  // prologue: buf0 <- A(0),B(0); buf1 <- B(1). vmcnt(4): B(1)'s 4 loads may remain.
  stage(gA,        lA,                0);
  stage(gA + H128, lA + 8192,         0);
  stage(gB,        lB,                0);
  stage(gB + H128, lB + 8192,         0);
  stage(gB,        lB + 16384,        1);
  stage(gB + H128, lB + 16384 + 8192, 1);
  asm volatile("s_waitcnt vmcnt(4)" ::: "memory");
  SBAR();

  #pragma unroll 1
  for (int i = 0; i < 8; i++){
    const int k0 = 2 * i;
    PHASE(0, 0, gA,        lA + 16384,        k0 + 1,        false);
    PHASE(0, 1, gA + H128, lA + 16384 + 8192, k0 + 1,        false);
    PHASE(0, 2, gB,        lB,                (k0 + 2) & 15, false);
    PHASE(0, 3, gB + H128, lB + 8192,         (k0 + 2) & 15, true);
    PHASE(1, 0, gA,        lA,                (k0 + 2) & 15, false);
    PHASE(1, 1, gA + H128, lA + 8192,         (k0 + 2) & 15, false);
    PHASE(1, 2, gB,        lB + 16384,        (k0 + 3) & 15, false);
    PHASE(1, 3, gB + H128, lB + 16384 + 8192, (k0 + 3) & 15, true);
  }

  const int r0 = kq * 4;
  #pragma unroll
  for (int mi = 0; mi < 8; mi++){
    #pragma unroll
    for (int nj = 0; nj < 4; nj++){
      const int gmb = m0 + wm * 128 + mi * 16 + r0;
      const int gn  = n0 + wn * 64 + nj * 16 + fr;
      #pragma unroll
      for (int r = 0; r < 4; r++){
        const int gm = gmb + r;
        const float x = acc[mi][nj][r];
        if (MODE == 0){
          if (gn < 1024){
            const float v = x + bias0[gn];
            og[(size_t)gm * DM + gn] = f2bf(1.0f / (1.0f + __expf(-v)));
          } else {
            const float v = x + bias1[gn - 1024];
            ot[(size_t)gm * DM + (gn - 1024)] = f2bf(v / (1.0f + __expf(-v)));
          }
        } else {
          const float v = x + bias0[gn];
          const float g = bf2f(gate[(size_t)gm * DM + gn]);
          of[(size_t)gm * DM + gn] = hsrc[(size_t)gm * DM + gn] + 0.5f * g * v;
        }
      }
    }
  }
}

// ---------- overwrite center row ----------
__global__ void k_fixc(const float* __restrict__ hcnew, const int* __restrict__ cidx,
                       float* __restrict__ out){
  int t = threadIdx.x;
  int c = *cidx;
  out[(size_t)c * DM + t] = hcnew[t];
}

extern "C" void kernel_launch(void* const* d_in, const int* in_sizes, int n_in,
                              void* d_out, int out_size, void* d_ws, size_t ws_size,
                              hipStream_t stream){
  const float* h      = (const float*)d_in[0];
  const float* rbf    = (const float*)d_in[1];
  const float* seqsep = (const float*)d_in[2];
  const float* localb = (const float*)d_in[3];
  const float* ncw    = (const float*)d_in[4];
  const float* ncb    = (const float*)d_in[5];
  const float* naw    = (const float*)d_in[6];
  const float* nab    = (const float*)d_in[7];
  const float* Wq     = (const float*)d_in[8];
  const float* Wk     = (const float*)d_in[9];
  const float* Wv     = (const float*)d_in[10];
  const float* Wo     = (const float*)d_in[11];
  const float* Wbias  = (const float*)d_in[12];
  const float* gateW  = (const float*)d_in[13];
  const float* gateB  = (const float*)d_in[14];
  const float* fuseW1 = (const float*)d_in[15];
  const float* fuseB1 = (const float*)d_in[16];
  const float* fuseW2 = (const float*)d_in[17];
  const float* fuseB2 = (const float*)d_in[18];
  const int*   nbr    = (const int*)d_in[19];
  const int*   cidx   = (const int*)d_in[20];
  float* out = (float*)d_out;

  char* p = (char*)d_ws;
  auto alloc = [&](size_t nb){ char* r = p; p += (nb + 255) & ~(size_t)255; return r; };
  float* extra  = (float*)alloc((size_t)NN * DEX * 4);
  float* logits = (float*)alloc((size_t)NH * NN * 4);
  float* meanb  = (float*)alloc((size_t)NN * 4);
  float* rstdb  = (float*)alloc((size_t)NN * 4);
  float* ms     = (float*)alloc(32 * 4);
  float* qkt    = (float*)alloc(NH * DM * 4);
  float* u      = (float*)alloc(NH * DM * 4);
  float* hcln   = (float*)alloc(DM * 4);
  float* qv     = (float*)alloc(DM * 4);
  float* oc     = (float*)alloc(DM * 4);
  float* hcnew  = (float*)alloc(DM * 4);
  float* gbtot  = (float*)alloc(DM * 4);
  float* fbtot  = (float*)alloc(DM * 4);
  float* c12    = (float*)alloc(32 * 4);
  float* upart  = (float*)alloc((size_t)UB * NH * DM * 4);
  unsigned short* Wcomb = (unsigned short*)alloc((size_t)2048 * 1024 * 2);
  unsigned short* W2b   = (unsigned short*)alloc((size_t)1024 * 1024 * 2);
  unsigned short* hbf   = (unsigned short*)alloc((size_t)NN * DM * 2);
  unsigned short* gateb = (unsigned short*)alloc((size_t)NN * DM * 2);
  unsigned short* t1    = (unsigned short*)alloc((size_t)NN * DM * 2);
  if ((size_t)(p - (char*)d_ws) > ws_size) return;  // clean fail instead of corruption

  hipMemsetAsync(extra, 0, (size_t)NN * DEX * 4, stream);
  k_scatter<<<(KNB * DEX + 255) / 256, 256, 0, stream>>>(localb, nbr, extra);
  k_convw<<<(3 * 1024 * 1024) / 256, 256, 0, stream>>>(gateW, fuseW1, fuseW2, Wcomb, W2b);
  k_cln<<<1, 256, 0, stream>>>(h, cidx, ncw, ncb, hcln);
  k_q<<<64, 256, 0, stream>>>(hcln, Wq, qv);
  k_qkt<<<64, 256, 0, stream>>>(qv, Wk, qkt);
  k_c12<<<32, 64, 0, stream>>>(qkt, naw, nab, c12);
  k_rowpass<<<NN / 8, 256, 0, stream>>>(h, naw, nab, rbf, seqsep, extra, Wbias, qkt, c12,
                                        logits, meanb, rstdb, hbf);
  k_smstats<<<16, 1024, 0, stream>>>(logits, ms);
  k_upart<<<UB, 256, 0, stream>>>(hbf, meanb, rstdb, naw, nab, logits, ms, upart);
  k_ureduce<<<64, 256, 0, stream>>>(upart, ms, u);
  k_oc<<<64, 256, 0, stream>>>(u, Wv, oc);
  k_delta<<<64, 256, 0, stream>>>(oc, Wo, h, cidx, hcnew);
  k_gbfb<<<64, 256, 0, stream>>>(hcnew, gateW, gateB, fuseW1, fuseB1, gbtot, fbtot);
  k_gemm<0><<<2048, 512, 0, stream>>>(hbf, Wcomb, gbtot, fbtot, nullptr, nullptr, gateb, t1, nullptr);
  k_gemm<1><<<1024, 512, 0, stream>>>(t1, W2b, fuseB2, nullptr, h, gateb, nullptr, nullptr, out);
  k_fixc<<<1, 1024, 0, stream>>>(hcnew, cidx, out);
}